// Round 2
// baseline (598.602 us; speedup 1.0000x reference)
//
#include <hip/hip_runtime.h>

// Entmax-1.5 over last axis. tau* is the root of
//   f(tau) = sum_i max(x_i - tau, 0)^2 - 1   (convex, piecewise quadratic, decreasing)
// Piecewise-exact (Michelot-style) root iteration:
//   u = (F-1) / (G + sqrt(G^2 - K*(F-1))),  F = sum y^2, G = sum y, K = #{y>0}
// Changes vs previous best (200 us/dispatch, VALUBusy 44%):
//  1. Packed-FP32 scans: float2 ext-vectors -> v_pk_fma_f32 / v_pk_add_f32 on gfx950
//     (halves sub/fma/add in the 32-reg scans).
//  2. K via __ballot + __popcll: per-element v_cmp only on VALU; popcount+accum on
//     SALU; kills the K shuffle-reduction chain (1 of 3 six-level chains per iter).
//  3. First exact step fused into the alpha-transform pass (one fewer full scan).
//  4. Nontemporal float4 stores (output is never re-read; keep L2/L3 for inputs).
//     NOTE: __builtin_nontemporal_store requires a clang ext-vector type, not
//     HIP's float4 struct -> use ext_vector_type(4) for the store.
// One wave per row of S=2048; 32 elems/lane in registers; shuffle reductions only.

#define NEG_FILL (-1.0e4f)

typedef float float2v __attribute__((ext_vector_type(2)));
typedef float float4v __attribute__((ext_vector_type(4)));

static constexpr int S_DIM = 2048;
static constexpr int WAVES_PER_BLOCK = 4;       // 256-thread blocks
static constexpr int ELEMS = S_DIM / 64;        // 32 floats per lane
static constexpr int VEC = ELEMS / 4;           // 8 float4 loads per lane
static constexpr int VEC2 = ELEMS / 2;          // 16 float2 chunks per lane

__global__ __launch_bounds__(256) void entmax15_kernel(
    const float* __restrict__ scores,
    const int*   __restrict__ mask,
    float*       __restrict__ out,
    int nrows)
{
    const int lane = threadIdx.x & 63;
    const int wave = threadIdx.x >> 6;
    const int row  = blockIdx.x * WAVES_PER_BLOCK + wave;
    if (row >= nrows) return;

    const size_t base = (size_t)row * S_DIM;
    const float4* __restrict__ srow = (const float4*)(scores + base);
    const int4*   __restrict__ mrow = (const int4*)(mask + base);
    float4v*      __restrict__ orow = (float4v*)(out + base);

    // ---- load + mask + row max (in registers) ----
    float x[ELEMS];
    float rmax = -3.402823466e38f;
#pragma unroll
    for (int j = 0; j < VEC; ++j) {
        const float4 s = srow[lane + 64 * j];
        const int4   m = mrow[lane + 64 * j];
        float v0 = m.x ? s.x : NEG_FILL;
        float v1 = m.y ? s.y : NEG_FILL;
        float v2 = m.z ? s.z : NEG_FILL;
        float v3 = m.w ? s.w : NEG_FILL;
        x[4 * j + 0] = v0;
        x[4 * j + 1] = v1;
        x[4 * j + 2] = v2;
        x[4 * j + 3] = v3;
        // nested fmaxf may fuse to v_max3_f32
        rmax = fmaxf(rmax, fmaxf(fmaxf(v0, v1), fmaxf(v2, v3)));
    }
#pragma unroll
    for (int off = 32; off >= 1; off >>= 1)
        rmax = fmaxf(rmax, __shfl_xor(rmax, off, 64));

    // ---- alpha=1.5 transform fused with first exact step at tau0=-1 ----
    // x = (x - max)*0.5  =>  max(x)==0, tau* in [-1, 0).  At tau=-1: d = x+1.
    // Masked elems sit at ~-5000 => y=0 there for all tau >= -1 automatically.
    const float shift = -0.5f * rmax;
    float2v* xv = (float2v*)x;

    const float2v h05  = {0.5f, 0.5f};
    const float2v sh2  = {shift, shift};
    const float2v one2 = {1.0f, 1.0f};
    const float2v zero2 = {0.0f, 0.0f};

    float2v F2 = zero2, G2 = zero2;
    int K = 0;
#pragma unroll
    for (int i = 0; i < VEC2; ++i) {
        float2v t = __builtin_elementwise_fma(xv[i], h05, sh2);   // v_pk_fma_f32
        xv[i] = t;
        float2v d = t + one2;                                      // v_pk_add_f32
        float2v y = __builtin_elementwise_max(d, zero2);
        F2 = __builtin_elementwise_fma(y, y, F2);                  // v_pk_fma_f32
        G2 = G2 + y;                                               // v_pk_add_f32
        // K on the scalar pipe: v_cmp -> sgpr mask, s_bcnt1 + s_add (no shuffle chain)
        K += __popcll(__ballot(d.x > 0.0f));
        K += __popcll(__ballot(d.y > 0.0f));
    }

    float2v FG;
    FG.x = F2.x + F2.y;
    FG.y = G2.x + G2.y;
#pragma unroll
    for (int off = 32; off >= 1; off >>= 1) {
        float2v t;
        t.x = __shfl_xor(FG.x, off, 64);
        t.y = __shfl_xor(FG.y, off, 64);
        FG += t;                                                   // v_pk_add_f32
    }

    float c     = FG.x - 1.0f;                     // F - 1 (>= 0 from below)
    float disc  = fmaf(FG.y, FG.y, -(float)K * c); // G^2 - K*(F-1)
    float denom = (disc > 0.0f) ? (FG.y + sqrtf(disc)) : (2.0f * FG.y);
    float u     = c / denom;
    float tau   = -1.0f + u;

    // ---- remaining piecewise-exact iterations (wave-uniform break) ----
#pragma unroll 1
    for (int it = 1; it < 16 && fabsf(u) > 2e-7f; ++it) {
        const float2v t2 = {tau, tau};
        F2 = zero2; G2 = zero2; K = 0;
#pragma unroll
        for (int i = 0; i < VEC2; ++i) {
            float2v d = xv[i] - t2;                                // v_pk_add_f32
            float2v y = __builtin_elementwise_max(d, zero2);
            F2 = __builtin_elementwise_fma(y, y, F2);              // v_pk_fma_f32
            G2 = G2 + y;                                           // v_pk_add_f32
            K += __popcll(__ballot(d.x > 0.0f));
            K += __popcll(__ballot(d.y > 0.0f));
        }
        FG.x = F2.x + F2.y;
        FG.y = G2.x + G2.y;
#pragma unroll
        for (int off = 32; off >= 1; off >>= 1) {
            float2v t;
            t.x = __shfl_xor(FG.x, off, 64);
            t.y = __shfl_xor(FG.y, off, 64);
            FG += t;
        }
        c     = FG.x - 1.0f;
        disc  = fmaf(FG.y, FG.y, -(float)K * c);
        denom = (disc > 0.0f) ? (FG.y + sqrtf(disc)) : (2.0f * FG.y);
        u     = c / denom;
        tau  += u;
    }

    // ---- epilogue: p = max(x - tau, 0)^2, coalesced nontemporal float4 stores ----
    const float2v t2 = {tau, tau};
#pragma unroll
    for (int j = 0; j < VEC; ++j) {
        float2v ya = __builtin_elementwise_max(xv[2 * j]     - t2, zero2);
        float2v yb = __builtin_elementwise_max(xv[2 * j + 1] - t2, zero2);
        float2v oa = ya * ya;                                      // v_pk_mul_f32
        float2v ob = yb * yb;
        float4v o;
        o.x = oa.x; o.y = oa.y; o.z = ob.x; o.w = ob.y;
        __builtin_nontemporal_store(o, &orow[lane + 64 * j]);
    }
}

extern "C" void kernel_launch(void* const* d_in, const int* in_sizes, int n_in,
                              void* d_out, int out_size, void* d_ws, size_t ws_size,
                              hipStream_t stream) {
    const float* scores = (const float*)d_in[0];
    const int*   mask   = (const int*)d_in[1];
    float*       out    = (float*)d_out;

    const int nrows = in_sizes[0] / S_DIM;  // 32768
    const int grid  = (nrows + WAVES_PER_BLOCK - 1) / WAVES_PER_BLOCK;

    entmax15_kernel<<<grid, 256, 0, stream>>>(scores, mask, out, nrows);
}

// Round 3
// 590.139 us; speedup vs baseline: 1.0143x; 1.0143x over previous
//
#include <hip/hip_runtime.h>

// Entmax-1.5 over last axis. tau* is the root of
//   f(tau) = sum_i max(x_i - tau, 0)^2 - 1   (convex, piecewise quadratic, decreasing)
// Piecewise-exact (Michelot-style) root iteration:
//   u = (F-1) / (G + sqrt(G^2 - K*(F-1))),  F = sum y^2, G = sum y, K = #{y>0}
//
// Round-2 finding: kernel is LATENCY-bound (VALUBusy 27%, HBM 31%, all pipes idle;
// per-wave VALU duty ~7%). Fix: 2 rows per wave, fully interleaved ->
//   - 32 independent global loads in flight per wave (2x MLP)
//   - two independent scan + shuffle-reduce chains (2x ILP, hides shuffle latency)
// Also reverted nontemporal stores (suspected round-1 regression contributor).
// Kept: packed-fp32 math (v_pk_fma/add), ballot+popc for K, fused first step.

#define NEG_FILL (-1.0e4f)

typedef float float2v __attribute__((ext_vector_type(2)));

static constexpr int S_DIM = 2048;
static constexpr int WAVES_PER_BLOCK = 4;       // 256-thread blocks
static constexpr int ROWS_PER_WAVE = 2;
static constexpr int ELEMS = S_DIM / 64;        // 32 floats per lane per row
static constexpr int VEC = ELEMS / 4;           // 8 float4 loads per lane per row
static constexpr int VEC2 = ELEMS / 2;          // 16 float2 chunks per lane per row

__global__ __launch_bounds__(256) void entmax15_kernel(
    const float* __restrict__ scores,
    const int*   __restrict__ mask,
    float*       __restrict__ out,
    int nrows)
{
    const int lane = threadIdx.x & 63;
    const int wave = threadIdx.x >> 6;
    const int rowA = (blockIdx.x * WAVES_PER_BLOCK + wave) * ROWS_PER_WAVE;
    if (rowA >= nrows) return;
    const bool hasB = (rowA + 1) < nrows;
    const int rowB = hasB ? (rowA + 1) : rowA;

    const size_t baseA = (size_t)rowA * S_DIM;
    const size_t baseB = (size_t)rowB * S_DIM;
    const float4* __restrict__ srowA = (const float4*)(scores + baseA);
    const int4*   __restrict__ mrowA = (const int4*)(mask + baseA);
    float4*       __restrict__ orowA = (float4*)(out + baseA);
    const float4* __restrict__ srowB = (const float4*)(scores + baseB);
    const int4*   __restrict__ mrowB = (const int4*)(mask + baseB);
    float4*       __restrict__ orowB = (float4*)(out + baseB);

    // ---- load + mask + row max, two rows interleaved ----
    float xA[ELEMS], xB[ELEMS];
    float rmaxA = -3.402823466e38f, rmaxB = -3.402823466e38f;
#pragma unroll
    for (int j = 0; j < VEC; ++j) {
        const float4 sa = srowA[lane + 64 * j];
        const int4   ma = mrowA[lane + 64 * j];
        const float4 sb = srowB[lane + 64 * j];
        const int4   mb = mrowB[lane + 64 * j];
        float a0 = ma.x ? sa.x : NEG_FILL;
        float a1 = ma.y ? sa.y : NEG_FILL;
        float a2 = ma.z ? sa.z : NEG_FILL;
        float a3 = ma.w ? sa.w : NEG_FILL;
        float b0 = mb.x ? sb.x : NEG_FILL;
        float b1 = mb.y ? sb.y : NEG_FILL;
        float b2 = mb.z ? sb.z : NEG_FILL;
        float b3 = mb.w ? sb.w : NEG_FILL;
        xA[4 * j + 0] = a0; xA[4 * j + 1] = a1; xA[4 * j + 2] = a2; xA[4 * j + 3] = a3;
        xB[4 * j + 0] = b0; xB[4 * j + 1] = b1; xB[4 * j + 2] = b2; xB[4 * j + 3] = b3;
        rmaxA = fmaxf(rmaxA, fmaxf(fmaxf(a0, a1), fmaxf(a2, a3)));
        rmaxB = fmaxf(rmaxB, fmaxf(fmaxf(b0, b1), fmaxf(b2, b3)));
    }
#pragma unroll
    for (int off = 32; off >= 1; off >>= 1) {
        rmaxA = fmaxf(rmaxA, __shfl_xor(rmaxA, off, 64));
        rmaxB = fmaxf(rmaxB, __shfl_xor(rmaxB, off, 64));
    }

    // ---- alpha=1.5 transform fused with first exact step at tau0=-1 ----
    // x = (x - max)*0.5  =>  max(x)==0, tau* in [-1, 0).  At tau=-1: d = x+1.
    const float2v h05   = {0.5f, 0.5f};
    const float2v one2  = {1.0f, 1.0f};
    const float2v zero2 = {0.0f, 0.0f};
    const float2v shA = {-0.5f * rmaxA, -0.5f * rmaxA};
    const float2v shB = {-0.5f * rmaxB, -0.5f * rmaxB};
    float2v* xvA = (float2v*)xA;
    float2v* xvB = (float2v*)xB;

    float2v FA = zero2, GA = zero2, FB = zero2, GB = zero2;
    int KA = 0, KB = 0;
#pragma unroll
    for (int i = 0; i < VEC2; ++i) {
        float2v ta = __builtin_elementwise_fma(xvA[i], h05, shA);
        float2v tb = __builtin_elementwise_fma(xvB[i], h05, shB);
        xvA[i] = ta;
        xvB[i] = tb;
        float2v da = ta + one2;
        float2v db = tb + one2;
        float2v ya = __builtin_elementwise_max(da, zero2);
        float2v yb = __builtin_elementwise_max(db, zero2);
        FA = __builtin_elementwise_fma(ya, ya, FA);
        FB = __builtin_elementwise_fma(yb, yb, FB);
        GA = GA + ya;
        GB = GB + yb;
        KA += __popcll(__ballot(da.x > 0.0f));
        KA += __popcll(__ballot(da.y > 0.0f));
        KB += __popcll(__ballot(db.x > 0.0f));
        KB += __popcll(__ballot(db.y > 0.0f));
    }

    // pack (F,G) per row; two independent butterfly chains interleave
    float2v RA, RB;
    RA.x = FA.x + FA.y; RA.y = GA.x + GA.y;
    RB.x = FB.x + FB.y; RB.y = GB.x + GB.y;
#pragma unroll
    for (int off = 32; off >= 1; off >>= 1) {
        float2v ta, tb;
        ta.x = __shfl_xor(RA.x, off, 64);
        ta.y = __shfl_xor(RA.y, off, 64);
        tb.x = __shfl_xor(RB.x, off, 64);
        tb.y = __shfl_xor(RB.y, off, 64);
        RA += ta;
        RB += tb;
    }

    float cA     = RA.x - 1.0f;
    float cB     = RB.x - 1.0f;
    float discA  = fmaf(RA.y, RA.y, -(float)KA * cA);
    float discB  = fmaf(RB.y, RB.y, -(float)KB * cB);
    float denA   = (discA > 0.0f) ? (RA.y + sqrtf(discA)) : (2.0f * RA.y);
    float denB   = (discB > 0.0f) ? (RB.y + sqrtf(discB)) : (2.0f * RB.y);
    float uA     = cA / denA;
    float uB     = cB / denB;
    float tauA   = -1.0f + uA;
    float tauB   = -1.0f + uB;

    // ---- remaining piecewise-exact iterations, both rows in lockstep ----
    // F,G,K are bitwise-identical across lanes (butterfly) -> wave-uniform break.
#pragma unroll 1
    for (int it = 1; it < 16; ++it) {
        if (!(fabsf(uA) > 2e-7f) && !(fabsf(uB) > 2e-7f)) break;
        const float2v tA2 = {tauA, tauA};
        const float2v tB2 = {tauB, tauB};
        FA = zero2; GA = zero2; FB = zero2; GB = zero2;
        KA = 0; KB = 0;
#pragma unroll
        for (int i = 0; i < VEC2; ++i) {
            float2v da = xvA[i] - tA2;
            float2v db = xvB[i] - tB2;
            float2v ya = __builtin_elementwise_max(da, zero2);
            float2v yb = __builtin_elementwise_max(db, zero2);
            FA = __builtin_elementwise_fma(ya, ya, FA);
            FB = __builtin_elementwise_fma(yb, yb, FB);
            GA = GA + ya;
            GB = GB + yb;
            KA += __popcll(__ballot(da.x > 0.0f));
            KA += __popcll(__ballot(da.y > 0.0f));
            KB += __popcll(__ballot(db.x > 0.0f));
            KB += __popcll(__ballot(db.y > 0.0f));
        }
        RA.x = FA.x + FA.y; RA.y = GA.x + GA.y;
        RB.x = FB.x + FB.y; RB.y = GB.x + GB.y;
#pragma unroll
        for (int off = 32; off >= 1; off >>= 1) {
            float2v ta, tb;
            ta.x = __shfl_xor(RA.x, off, 64);
            ta.y = __shfl_xor(RA.y, off, 64);
            tb.x = __shfl_xor(RB.x, off, 64);
            tb.y = __shfl_xor(RB.y, off, 64);
            RA += ta;
            RB += tb;
        }
        cA    = RA.x - 1.0f;
        cB    = RB.x - 1.0f;
        discA = fmaf(RA.y, RA.y, -(float)KA * cA);
        discB = fmaf(RB.y, RB.y, -(float)KB * cB);
        denA  = (discA > 0.0f) ? (RA.y + sqrtf(discA)) : (2.0f * RA.y);
        denB  = (discB > 0.0f) ? (RB.y + sqrtf(discB)) : (2.0f * RB.y);
        uA    = cA / denA;
        uB    = cB / denB;
        tauA += uA;
        tauB += uB;
    }

    // ---- epilogue: p = max(x - tau, 0)^2, coalesced float4 stores ----
    const float2v tA2 = {tauA, tauA};
    const float2v tB2 = {tauB, tauB};
#pragma unroll
    for (int j = 0; j < VEC; ++j) {
        float2v ya0 = __builtin_elementwise_max(xvA[2 * j]     - tA2, zero2);
        float2v ya1 = __builtin_elementwise_max(xvA[2 * j + 1] - tA2, zero2);
        float2v oa0 = ya0 * ya0;
        float2v oa1 = ya1 * ya1;
        float4 oa;
        oa.x = oa0.x; oa.y = oa0.y; oa.z = oa1.x; oa.w = oa1.y;
        orowA[lane + 64 * j] = oa;
    }
    if (hasB) {
#pragma unroll
        for (int j = 0; j < VEC; ++j) {
            float2v yb0 = __builtin_elementwise_max(xvB[2 * j]     - tB2, zero2);
            float2v yb1 = __builtin_elementwise_max(xvB[2 * j + 1] - tB2, zero2);
            float2v ob0 = yb0 * yb0;
            float2v ob1 = yb1 * yb1;
            float4 ob;
            ob.x = ob0.x; ob.y = ob0.y; ob.z = ob1.x; ob.w = ob1.y;
            orowB[lane + 64 * j] = ob;
        }
    }
}

extern "C" void kernel_launch(void* const* d_in, const int* in_sizes, int n_in,
                              void* d_out, int out_size, void* d_ws, size_t ws_size,
                              hipStream_t stream) {
    const float* scores = (const float*)d_in[0];
    const int*   mask   = (const int*)d_in[1];
    float*       out    = (float*)d_out;

    const int nrows = in_sizes[0] / S_DIM;  // 32768
    const int rows_per_block = WAVES_PER_BLOCK * ROWS_PER_WAVE;
    const int grid = (nrows + rows_per_block - 1) / rows_per_block;

    entmax15_kernel<<<grid, 256, 0, stream>>>(scores, mask, out, nrows);
}